// Round 6
// baseline (3698.145 us; speedup 1.0000x reference)
//
#include <hip/hip_runtime.h>
#include <hip/hip_fp16.h>

// DNCClassifier: DNC memory machinery is dead code; output = LSTM-final-h @
// W_fc.T + b_fc.  gates_t = x_t@W_ih[:,:27].T + (b_ih+b_hh) + h@W_hh.T
// B=128, T=512, IN=27, H=256 (4H=1024), OUT=128.
//
// R12: structural rewrite. R7-R11 proved the 1-batch-per-CU VALU-dot
// structure is pinned at ~855us regardless of LDS volume, barrier count,
// VALU count, or phase order. New structure: 8 blocks x 1024 thr (16 waves);
// each block runs a 16-row batch tile; the per-step h@W_hh.T is done with
// mfma_f32_16x16x32_f16. Weights live as per-wave MFMA B-fragments in the
// register file (128 VGPR/wave; MFMA reads AGPR natively so the arch/acc
// split is harmless). h is exchanged via a 16KB XOR-swizzled LDS double
// buffer (8 ds_read_b128/thread/step). P is pre-packed by prep_p in the
// MFMA C/D fragment layout and seeded as the MFMA C operand. Per-gate
// nonlinearity in unified lane-constant form, then a 4x4 DPP quad transpose
// gathers (i,f,g,o) of one (unit,row) per lane for the c/h update.
// One barrier/step. k-index packing convention is IDENTICAL for A and B
// fragments, so the MFMA contraction is invariant to it; row/col = lane&15
// per the verified C/D mapping.

typedef _Float16 h2t __attribute__((ext_vector_type(2)));
typedef _Float16 half8 __attribute__((ext_vector_type(8)));
typedef float f32x4 __attribute__((ext_vector_type(4)));

__device__ __forceinline__ h2t bc2(unsigned int v) {
  union { unsigned int u; h2t h; } x; x.u = v; return x.h;
}
__device__ __forceinline__ unsigned int pk(float a, float b) {
  union { h2t h; unsigned int u; } x;
  x.h[0] = (_Float16)a; x.h[1] = (_Float16)b;
  return x.u;
}
__device__ __forceinline__ float fdot2f(h2t a, h2t b, float c) {
#if defined(__has_builtin)
#if __has_builtin(__builtin_amdgcn_fdot2)
  return __builtin_amdgcn_fdot2(a, b, c, false);
#else
  return c + (float)a[0] * (float)b[0] + (float)a[1] * (float)b[1];
#endif
#else
  return c + (float)a[0] * (float)b[0] + (float)a[1] * (float)b[1];
#endif
}
__device__ __forceinline__ float exp2f_(float x) {
#if defined(__has_builtin)
#if __has_builtin(__builtin_amdgcn_exp2f)
  return __builtin_amdgcn_exp2f(x);
#else
  return __expf(0.69314718056f * x);
#endif
#else
  return __expf(0.69314718056f * x);
#endif
}
// quad_perm DPP: xor-1 / xor-2 within each 4-lane group
__device__ __forceinline__ float dpp_x1(float x) {
  return __int_as_float(
      __builtin_amdgcn_mov_dpp(__float_as_int(x), 0xB1, 0xF, 0xF, true));
}
__device__ __forceinline__ float dpp_x2(float x) {
  return __int_as_float(
      __builtin_amdgcn_mov_dpp(__float_as_int(x), 0x4E, 0xF, 0xF, true));
}

// ---- workspace layout (bytes) ----
// P: uint2[ (((t*8+b)*16+w)*4+ct)*64 + l ] : 4 fp16 gate values (rows
//    hi*4+0..3 of one gate-column), bias + x-projection folded. 128 MiB.
// W: fp16 MFMA B-fragments [ (((w*4+ct)*8+kt)*64+l)*8 + j ]. 512 KiB.
#define WS_P_OFF   0ull
#define WS_W_OFF   134217728ull
#define WS_NEED    134742016ull
#define PSTRIDE    262144           // P byte stride per t step

// Column space: wave w owns 64 cols; col-local = ct*16 + lo (lo = l&15).
// unit q = w*16 + ct*4 + (lo>>2); gate g = lo&3 (torch row = g*256+q).
// k packing (A and B identical): within k-tile kt, element j of lane l is
// k = kt*32 + (l>>4)*8 + j.

__global__ void prep_w(const float* __restrict__ W_hh,
                       unsigned char* __restrict__ ws) {
  int idx = blockIdx.x * 256 + threadIdx.x;   // 512 blocks -> 131072 uints
  int j2 = idx & 3;
  int l  = (idx >> 2) & 63;
  int kt = (idx >> 8) & 7;
  int ct = (idx >> 11) & 3;
  int w  = (idx >> 13) & 15;
  int lo = l & 15, hi = l >> 4;
  int q = w * 16 + ct * 4 + (lo >> 2);
  int g = lo & 3;
  int row = g * 256 + q;
  int k = kt * 32 + hi * 8 + 2 * j2;
  ((unsigned int*)(ws + WS_W_OFF))[idx] =
      pk(W_hh[row * 256 + k], W_hh[row * 256 + k + 1]);
}

// P in C/D fragment layout. Block = one t; 1024 threads cover (w,ct,l) in 4
// passes; inner loop over the 8 batch tiles.
__global__ __launch_bounds__(1024) void prep_p(
    const float* __restrict__ x, const float* __restrict__ W_ih,
    const float* __restrict__ b_ih, const float* __restrict__ b_hh,
    unsigned char* __restrict__ ws) {
  __shared__ unsigned int sX[128][14];
  const int v = threadIdx.x;
  const int t = blockIdx.x;
#pragma unroll 1
  for (int i = v; i < 1792; i += 1024) {      // stage all 128 rows of x_t
    int row = i / 14, c2 = i - 14 * row;
    const float* xr = x + ((size_t)row * 512 + t) * 27;
    float a = xr[2 * c2];
    float bb = (2 * c2 + 1 < 27) ? xr[2 * c2 + 1] : 0.f;
    sX[row][c2] = pk(a, bb);
  }
  __syncthreads();
  uint2* Pout = (uint2*)(ws + WS_P_OFF);
#pragma unroll 1
  for (int o4 = 0; o4 < 4; ++o4) {
    int idx = o4 * 1024 + v;
    int w = idx >> 8, ct = (idx >> 6) & 3, l = idx & 63;
    int lo = l & 15, hi = l >> 4;
    int q = w * 16 + ct * 4 + (lo >> 2);
    int g = lo & 3;
    int wrow = g * 256 + q;
    float bias = b_ih[wrow] + b_hh[wrow];
    unsigned int wih[14];
    const float* rowp = W_ih + (size_t)wrow * 47;
#pragma unroll
    for (int j = 0; j < 14; ++j) {
      float a = rowp[2 * j];
      float bb = (2 * j + 1 < 27) ? rowp[2 * j + 1] : 0.f;
      wih[j] = pk(a, bb);
    }
#pragma unroll 1
    for (int bb = 0; bb < 8; ++bb) {
      float a0 = bias, a1 = bias, a2 = bias, a3 = bias;
      int r0 = bb * 16 + hi * 4;
#pragma unroll
      for (int j = 0; j < 14; ++j) {
        h2t wj = bc2(wih[j]);
        a0 = fdot2f(wj, bc2(sX[r0 + 0][j]), a0);
        a1 = fdot2f(wj, bc2(sX[r0 + 1][j]), a1);
        a2 = fdot2f(wj, bc2(sX[r0 + 2][j]), a2);
        a3 = fdot2f(wj, bc2(sX[r0 + 3][j]), a3);
      }
      uint2 o; o.x = pk(a0, a1); o.y = pk(a2, a3);
      Pout[((((size_t)t * 8 + bb) * 16 + w) * 4 + ct) * 64 + l] = o;
    }
  }
}

// Persistent MFMA LSTM scan. 8 blocks x 1024 thr (16 waves, one batch-16
// tile per block). h double buffer: [2][16 rows][32 slots of 16B], physical
// slot = (kt*4+hi) ^ row (XOR swizzle -> ~2-way max on A reads).
__global__ __launch_bounds__(1024, 1) void scan_k(
    const unsigned char* __restrict__ ws, const float* __restrict__ W_fc,
    const float* __restrict__ b_fc, float* __restrict__ out) {
  __shared__ __align__(16) unsigned char hlds[2 * 8192];
  __shared__ float sHF[16][256];
  const int v = threadIdx.x;
  const int b = blockIdx.x;
  const int l = v & 63;
  const int w = v >> 6;
  const int lo = l & 15;
  const int hi = l >> 4;

  // --- B-fragments: full W_hh in registers (32 x half8 = 128 VGPR) ---
  half8 bfr[32];
  {
    const half8* Wg = (const half8*)(ws + WS_W_OFF);
#pragma unroll
    for (int ct = 0; ct < 4; ++ct)
#pragma unroll
      for (int kt = 0; kt < 8; ++kt)
        bfr[ct * 8 + kt] = Wg[((w * 4 + ct) * 8 + kt) * 64 + l];
  }
  // A-read addresses (buffer 0 byte offsets)
  int a_0 = lo * 512 + (((0 * 4 + hi) ^ lo) << 4);
  int a_1 = lo * 512 + (((1 * 4 + hi) ^ lo) << 4);
  int a_2 = lo * 512 + (((2 * 4 + hi) ^ lo) << 4);
  int a_3 = lo * 512 + (((3 * 4 + hi) ^ lo) << 4);
  int a_4 = lo * 512 + (((4 * 4 + hi) ^ lo) << 4);
  int a_5 = lo * 512 + (((5 * 4 + hi) ^ lo) << 4);
  int a_6 = lo * 512 + (((6 * 4 + hi) ^ lo) << 4);
  int a_7 = lo * 512 + (((7 * 4 + hi) ^ lo) << 4);
  // h write addresses per tile (row_t = hi*4 + (l&3))
  const int row_t = hi * 4 + (l & 3);
  const int q0 = w * 16 + 0 * 4 + (lo >> 2);
  const int q1 = w * 16 + 1 * 4 + (lo >> 2);
  const int q2 = w * 16 + 2 * 4 + (lo >> 2);
  const int q3 = w * 16 + 3 * 4 + (lo >> 2);
  const int wa0 = row_t * 512 + (((q0 >> 3) ^ row_t) << 4) + (q0 & 7) * 2;
  const int wa1 = row_t * 512 + (((q1 >> 3) ^ row_t) << 4) + (q1 & 7) * 2;
  const int wa2 = row_t * 512 + (((q2 >> 3) ^ row_t) << 4) + (q2 & 7) * 2;
  const int wa3 = row_t * 512 + (((q3 >> 3) ^ row_t) << 4) + (q3 & 7) * 2;
  // nonlinearity lane constants (gate g = lo&3; g==2 -> tanh, else sigmoid)
  const int g = lo & 3;
  const float s2v = (g == 2) ? 2.885390082f : -1.442695041f;
  const float Av  = (g == 2) ? -2.f : 1.f;
  const float Bv  = (g == 2) ? 1.f : 0.f;
  const bool c1m = (l & 1) != 0;
  const bool c2m = (l & 2) != 0;

  // zero both h buffers
  ((uint4*)hlds)[v] = make_uint4(0u, 0u, 0u, 0u);

  // P pointers (one per tile), t=0
  const unsigned char* pp0 = ws + WS_P_OFF +
      ((((size_t)b * 16 + w) * 4 + 0) * 64 + l) * 8;
  const unsigned char* pp1 = pp0 + 64 * 8;
  const unsigned char* pp2 = pp0 + 2 * 64 * 8;
  const unsigned char* pp3 = pp0 + 3 * 64 * 8;
  uint2 pc0 = *(const uint2*)pp0; pp0 += PSTRIDE;
  uint2 pc1 = *(const uint2*)pp1; pp1 += PSTRIDE;
  uint2 pc2 = *(const uint2*)pp2; pp2 += PSTRIDE;
  uint2 pc3 = *(const uint2*)pp3; pp3 += PSTRIDE;
  uint2 pn0, pn1, pn2, pn3;
  float c0 = 0.f, c1 = 0.f, c2 = 0.f, c3 = 0.f;
  float hl0 = 0.f, hl1 = 0.f, hl2 = 0.f, hl3 = 0.f;
  __syncthreads();

#define NL(xv) __builtin_fmaf(Av, __builtin_amdgcn_rcpf(1.f + exp2f_(s2v * (xv))), Bv)

#define TILE(CT, PC, CREG, WBOFF) do {                                        \
    h2t p01 = bc2(PC.x), p23 = bc2(PC.y);                                     \
    f32x4 acc;                                                                \
    acc[0] = (float)p01[0]; acc[1] = (float)p01[1];                           \
    acc[2] = (float)p23[0]; acc[3] = (float)p23[1];                           \
    acc = __builtin_amdgcn_mfma_f32_16x16x32_f16(af0, bfr[CT*8+0], acc,0,0,0);\
    acc = __builtin_amdgcn_mfma_f32_16x16x32_f16(af1, bfr[CT*8+1], acc,0,0,0);\
    acc = __builtin_amdgcn_mfma_f32_16x16x32_f16(af2, bfr[CT*8+2], acc,0,0,0);\
    acc = __builtin_amdgcn_mfma_f32_16x16x32_f16(af3, bfr[CT*8+3], acc,0,0,0);\
    acc = __builtin_amdgcn_mfma_f32_16x16x32_f16(af4, bfr[CT*8+4], acc,0,0,0);\
    acc = __builtin_amdgcn_mfma_f32_16x16x32_f16(af5, bfr[CT*8+5], acc,0,0,0);\
    acc = __builtin_amdgcn_mfma_f32_16x16x32_f16(af6, bfr[CT*8+6], acc,0,0,0);\
    acc = __builtin_amdgcn_mfma_f32_16x16x32_f16(af7, bfr[CT*8+7], acc,0,0,0);\
    float y0 = NL(acc[0]), y1 = NL(acc[1]), y2 = NL(acc[2]), y3 = NL(acc[3]); \
    float d0 = dpp_x1(y0), d1 = dpp_x1(y1), d2 = dpp_x1(y2), d3 = dpp_x1(y3); \
    float t0 = c1m ? d1 : y0, t1 = c1m ? y1 : d0;                             \
    float t2 = c1m ? d3 : y2, t3 = c1m ? y3 : d2;                             \
    float e0 = dpp_x2(t0), e1 = dpp_x2(t1), e2 = dpp_x2(t2), e3 = dpp_x2(t3); \
    float z0 = c2m ? e2 : t0, z2 = c2m ? t2 : e0;                             \
    float z1 = c2m ? e3 : t1, z3 = c2m ? t3 : e1;                             \
    CREG = __builtin_fmaf(z1, CREG, z0 * z2);                                 \
    float ee = exp2f_(CREG * 2.885390082f);                                   \
    float tc = __builtin_fmaf(-2.f, __builtin_amdgcn_rcpf(1.f + ee), 1.f);    \
    float hh = z3 * tc;                                                       \
    hl##CT = hh;                                                              \
    *(_Float16*)(hlds + (WBOFF) + wa##CT) = (_Float16)hh;                     \
  } while (0)

#define STEP(RBOFF, WBOFF, PC, PN) {                                          \
    PN##0 = *(const uint2*)pp0; pp0 += PSTRIDE;                               \
    PN##1 = *(const uint2*)pp1; pp1 += PSTRIDE;                               \
    PN##2 = *(const uint2*)pp2; pp2 += PSTRIDE;                               \
    PN##3 = *(const uint2*)pp3; pp3 += PSTRIDE;                               \
    half8 af0 = *(const half8*)(hlds + (RBOFF) + a_0);                        \
    half8 af1 = *(const half8*)(hlds + (RBOFF) + a_1);                        \
    half8 af2 = *(const half8*)(hlds + (RBOFF) + a_2);                        \
    half8 af3 = *(const half8*)(hlds + (RBOFF) + a_3);                        \
    half8 af4 = *(const half8*)(hlds + (RBOFF) + a_4);                        \
    half8 af5 = *(const half8*)(hlds + (RBOFF) + a_5);                        \
    half8 af6 = *(const half8*)(hlds + (RBOFF) + a_6);                        \
    half8 af7 = *(const half8*)(hlds + (RBOFF) + a_7);                        \
    TILE(0, PC##0, c0, WBOFF);                                                \
    TILE(1, PC##1, c1, WBOFF);                                                \
    TILE(2, PC##2, c2, WBOFF);                                                \
    TILE(3, PC##3, c3, WBOFF);                                                \
    __syncthreads();                                                          \
  }

#pragma unroll 1
  for (int it = 0; it < 256; ++it) {
    STEP(0, 8192, pc, pn)       // even t: read buf0, write buf1
    STEP(8192, 0, pn, pc)       // odd t : read buf1, write buf0
  }

  // --- classifier head on final h (f32, kept from last step) ---
  sHF[row_t][q0] = hl0;
  sHF[row_t][q1] = hl1;
  sHF[row_t][q2] = hl2;
  sHF[row_t][q3] = hl3;
  __syncthreads();
  {
    const int o = v & 127;
    const int rr = v >> 7;                     // 0..7 -> rows rr, rr+8
    float acc0 = b_fc[o], acc1 = acc0;
    const f32x4* wp = (const f32x4*)(W_fc + (size_t)o * 256);
    const f32x4* hA = (const f32x4*)(&sHF[rr][0]);
    const f32x4* hB = (const f32x4*)(&sHF[rr + 8][0]);
#pragma unroll 8
    for (int s = 0; s < 64; ++s) {
      f32x4 wq = wp[s];
      f32x4 ha = hA[s];
      f32x4 hb = hB[s];
      acc0 += wq[0]*ha[0] + wq[1]*ha[1] + wq[2]*ha[2] + wq[3]*ha[3];
      acc1 += wq[0]*hb[0] + wq[1]*hb[1] + wq[2]*hb[2] + wq[3]*hb[3];
    }
    out[((size_t)b * 16 + rr) * 128 + o] = acc0;
    out[((size_t)b * 16 + rr + 8) * 128 + o] = acc1;
  }
#undef STEP
#undef TILE
#undef NL
}

extern "C" void kernel_launch(void* const* d_in, const int* in_sizes, int n_in,
                              void* d_out, int out_size, void* d_ws,
                              size_t ws_size, hipStream_t stream) {
  const float* x    = (const float*)d_in[0];
  // d_in[1] = input_lengths: unused by the reference
  const float* W_ih = (const float*)d_in[2];
  const float* W_hh = (const float*)d_in[3];
  const float* b_ih = (const float*)d_in[4];
  const float* b_hh = (const float*)d_in[5];
  // d_in[6] = W_xi, d_in[7] = b_xi: dead code in the reference
  const float* W_fc = (const float*)d_in[8];
  const float* b_fc = (const float*)d_in[9];
  unsigned char* ws = (unsigned char*)d_ws;

  if (ws_size < WS_NEED) return;  // signature: output stays poisoned

  prep_w<<<512, 256, 0, stream>>>(W_hh, ws);
  prep_p<<<512, 1024, 0, stream>>>(x, W_ih, b_ih, b_hh, ws);
  scan_k<<<8, 1024, 0, stream>>>(ws, W_fc, b_fc, (float*)d_out);
}

// Round 8
// 1111.341 us; speedup vs baseline: 3.3276x; 3.3276x over previous
//
#include <hip/hip_runtime.h>
#include <hip/hip_fp16.h>
#include <hip/hip_fp8.h>

// DNCClassifier: DNC memory machinery is dead code; output = LSTM-final-h @
// W_fc.T + b_fc.  gates_t = x_t@W_ih[:,:27].T + (b_ih+b_hh) + h@W_hh.T
// B=128, T=512, IN=27, H=256 (4H=1024), OUT=128.
//
// R14 = R13 with the compile error fixed: __builtin_amdgcn_cvt_pk_fp8_f32's
// word-select operand must be an ICE at the call site -> template<bool HI>
// wrapper instead of a runtime bool parameter. Design unchanged:
//  - R12 passed correctness (MFMA layouts verified) but spilled its bf16
//    B-frags (64-reg budget at launch_bounds(1024,1)). bf16 weights (512KB)
//    can never be fully register-resident; fp8 e4m3 (256KB) can: 64 regs of
//    B-frags/wave, ~124 regs total state, within the 128-reg budget pinned
//    by __launch_bounds__(1024,4) + amdgpu_waves_per_eu(4,4).
//  - mfma_f32_16x16x32_fp8_fp8; weights and h scaled x8 into e4m3 normal
//    range; /64 folded into the gate fma before the nonlinearity.
//  - gate-per-tile columns: tile g holds gate g of the wave's 16 units ->
//    lane's 4 acc regs across tiles = (i,f,g,o) of ONE unit, 4 batch rows.
//    No cross-lane transpose at all.
//  - h LDS: fp8 [row][unit], row pad 272 B -> conflict-free b64 A-reads;
//    4 b8 scattered writes (small).
//  - P pre-packed in C/D fragment layout (fp16, unscaled), loaded per step.

typedef _Float16 h2t __attribute__((ext_vector_type(2)));
typedef float f32x4 __attribute__((ext_vector_type(4)));
typedef unsigned long long u64;

__device__ __forceinline__ h2t bc2(unsigned int v) {
  union { unsigned int u; h2t h; } x; x.u = v; return x.h;
}
__device__ __forceinline__ unsigned int pk(float a, float b) {
  union { h2t h; unsigned int u; } x;
  x.h[0] = (_Float16)a; x.h[1] = (_Float16)b;
  return x.u;
}
__device__ __forceinline__ float fdot2f(h2t a, h2t b, float c) {
#if defined(__has_builtin) && __has_builtin(__builtin_amdgcn_fdot2)
  return __builtin_amdgcn_fdot2(a, b, c, false);
#else
  return c + (float)a[0] * (float)b[0] + (float)a[1] * (float)b[1];
#endif
}
// fp8 e4m3 pack: bytes[0,1] (HI=false) or bytes[2,3] (HI=true) = fp8(a),fp8(b)
// word-select must be an integral constant expression -> template parameter.
template <bool HI>
__device__ __forceinline__ unsigned int pk_fp8x2(float a, float b,
                                                 unsigned int old) {
#if defined(__has_builtin) && __has_builtin(__builtin_amdgcn_cvt_pk_fp8_f32)
  return __builtin_amdgcn_cvt_pk_fp8_f32(a, b, old, HI);
#else
  __hip_fp8_e4m3 fa(a), fb(b);
  unsigned int v = (unsigned int)*(unsigned char*)&fa |
                   ((unsigned int)*(unsigned char*)&fb << 8);
  return HI ? ((old & 0x0000FFFFu) | (v << 16)) : ((old & 0xFFFF0000u) | v);
#endif
}
// rcp-based activations (R11-verified): no divides.
__device__ __forceinline__ float sigmf_(float x) {
  float e = __expf(-x);
  return __builtin_amdgcn_rcpf(1.f + e);
}
__device__ __forceinline__ float tanhf_(float x) {
  float e = __expf(2.f * x);
  float r = __builtin_amdgcn_rcpf(1.f + e);
  return __builtin_fmaf(-2.f, r, 1.f);
}

// ---- workspace layout (bytes) ----
// P: uint2[ (((t*8+bblk)*16+w)*4+g)*64 + l ] : 4 fp16 gate pre-activations
//    (batch rows (l>>4)*4+0..3 of gate g, unit w*16+(l&15)); bias folded.
// W: fp8 B-frags u64[ ((w*4+g)*8+kt)*64 + l ] : 8 bytes = k (l>>4)*8+0..7
//    of col l&15 (unit), scaled x8, e4m3. 256 KiB.
#define WS_P_OFF   0ull
#define WS_W_OFF   134217728ull
#define WS_NEED    134742016ull
#define PSTRIDE    262144ull     // per-t P stride = 8*16*4*64*8
#define INV64      0.015625f     // undo x8*x8 operand scaling

__global__ void prep_w(const float* __restrict__ W_hh,
                       unsigned char* __restrict__ ws) {
  int idx = blockIdx.x * 256 + threadIdx.x;   // 128 blocks -> 32768 u64
  int l = idx & 63, kt = (idx >> 6) & 7, g = (idx >> 9) & 3, w = idx >> 11;
  int row = g * 256 + w * 16 + (l & 15);
  int kb = kt * 32 + (l >> 4) * 8;
  const float* p = W_hh + (size_t)row * 256 + kb;
  unsigned int lo = pk_fp8x2<false>(8.f * p[0], 8.f * p[1], 0u);
  lo = pk_fp8x2<true>(8.f * p[2], 8.f * p[3], lo);
  unsigned int hi = pk_fp8x2<false>(8.f * p[4], 8.f * p[5], 0u);
  hi = pk_fp8x2<true>(8.f * p[6], 8.f * p[7], hi);
  ((uint2*)(ws + WS_W_OFF))[idx] = make_uint2(lo, hi);
}

// P in MFMA C/D fragment layout, fp16, bias folded. Block = one t.
__global__ __launch_bounds__(1024) void prep_p(
    const float* __restrict__ x, const float* __restrict__ W_ih,
    const float* __restrict__ b_ih, const float* __restrict__ b_hh,
    unsigned char* __restrict__ ws) {
  __shared__ unsigned int sX[128][14];
  const int v = threadIdx.x;
  const int t = blockIdx.x;
#pragma unroll 1
  for (int i = v; i < 1792; i += 1024) {      // stage all 128 rows of x_t
    int row = i / 14, c2 = i - 14 * row;
    const float* xr = x + ((size_t)row * 512 + t) * 27;
    float a = xr[2 * c2];
    float bb = (2 * c2 + 1 < 27) ? xr[2 * c2 + 1] : 0.f;
    sX[row][c2] = pk(a, bb);
  }
  __syncthreads();
  const int w = v >> 6, l = v & 63, lo = l & 15, hi = l >> 4;
  const int q = w * 16 + lo;
  uint2* Pout = (uint2*)(ws + WS_P_OFF);
#pragma unroll 1
  for (int g = 0; g < 4; ++g) {
    int wrow = g * 256 + q;
    float bias = b_ih[wrow] + b_hh[wrow];
    unsigned int wih[14];
    const float* rowp = W_ih + (size_t)wrow * 47;
#pragma unroll
    for (int j = 0; j < 14; ++j) {
      float a = rowp[2 * j];
      float bb = (2 * j + 1 < 27) ? rowp[2 * j + 1] : 0.f;
      wih[j] = pk(a, bb);
    }
#pragma unroll 1
    for (int bb8 = 0; bb8 < 8; ++bb8) {
      int r0 = bb8 * 16 + hi * 4;
      float a0 = bias, a1 = bias, a2 = bias, a3 = bias;
#pragma unroll
      for (int j = 0; j < 14; ++j) {
        h2t wj = bc2(wih[j]);
        a0 = fdot2f(wj, bc2(sX[r0 + 0][j]), a0);
        a1 = fdot2f(wj, bc2(sX[r0 + 1][j]), a1);
        a2 = fdot2f(wj, bc2(sX[r0 + 2][j]), a2);
        a3 = fdot2f(wj, bc2(sX[r0 + 3][j]), a3);
      }
      uint2 o; o.x = pk(a0, a1); o.y = pk(a2, a3);
      Pout[((((size_t)t * 8 + bb8) * 16 + w) * 4 + g) * 64 + l] = o;
    }
  }
}

// Persistent fp8-MFMA LSTM scan. 8 blocks x 1024 thr (16 waves, 4/SIMD,
// 128-reg budget pinned). Wave w owns units w*16..w*16+15, all 4 gates
// (tile g = gate g). h dbuf: fp8 [16 rows][272 B] per buffer (4352 B).
__global__ __launch_bounds__(1024, 4)
__attribute__((amdgpu_waves_per_eu(4, 4))) void scan_k(
    const unsigned char* __restrict__ ws, const float* __restrict__ W_fc,
    const float* __restrict__ b_fc, float* __restrict__ out) {
  __shared__ __align__(16) unsigned char hbuf[2 * 4352];
  __shared__ float sHF[16][256];
  const int v = threadIdx.x;
  const int b = blockIdx.x;
  const int l = v & 63;
  const int w = v >> 6;
  const int lo = l & 15;
  const int hi = l >> 4;
  const int q = w * 16 + lo;                   // this lane's unit

  // --- B-fragments: full fp8 W_hh in registers (32 x u64 = 64 regs) ---
  u64 bfr[32];
  {
    const u64* Wg = (const u64*)(ws + WS_W_OFF);
#pragma unroll
    for (int i = 0; i < 32; ++i)               // i = g*8 + kt
      bfr[i] = Wg[((w * 4 + (i >> 3)) * 8 + (i & 7)) * 64 + l];
  }
#pragma unroll 1
  for (int i = v; i < 2176; i += 1024) ((int*)hbuf)[i] = 0;  // zero h dbuf

  const int base_a = lo * 272 + hi * 8;        // A-read base (row lo)
  const int base_w = (hi * 4) * 272 + q;       // h-write base (rows hi*4+j)
  const unsigned char* pp = ws + WS_P_OFF +
      ((((size_t)b * 16 + w) * 4) * 64 + l) * 8;
  float c0 = 0.f, c1 = 0.f, c2 = 0.f, c3 = 0.f;
  float hl0 = 0.f, hl1 = 0.f, hl2 = 0.f, hl3 = 0.f;
  __syncthreads();

#define MFMA8(ACC, G, A0,A1,A2,A3,A4,A5,A6,A7)                               \
    ACC = __builtin_amdgcn_mfma_f32_16x16x32_fp8_fp8((long long)A0,          \
          (long long)bfr[(G)*8+0], ACC, 0, 0, 0);                            \
    ACC = __builtin_amdgcn_mfma_f32_16x16x32_fp8_fp8((long long)A1,          \
          (long long)bfr[(G)*8+1], ACC, 0, 0, 0);                            \
    ACC = __builtin_amdgcn_mfma_f32_16x16x32_fp8_fp8((long long)A2,          \
          (long long)bfr[(G)*8+2], ACC, 0, 0, 0);                            \
    ACC = __builtin_amdgcn_mfma_f32_16x16x32_fp8_fp8((long long)A3,          \
          (long long)bfr[(G)*8+3], ACC, 0, 0, 0);                            \
    ACC = __builtin_amdgcn_mfma_f32_16x16x32_fp8_fp8((long long)A4,          \
          (long long)bfr[(G)*8+4], ACC, 0, 0, 0);                            \
    ACC = __builtin_amdgcn_mfma_f32_16x16x32_fp8_fp8((long long)A5,          \
          (long long)bfr[(G)*8+5], ACC, 0, 0, 0);                            \
    ACC = __builtin_amdgcn_mfma_f32_16x16x32_fp8_fp8((long long)A6,          \
          (long long)bfr[(G)*8+6], ACC, 0, 0, 0);                            \
    ACC = __builtin_amdgcn_mfma_f32_16x16x32_fp8_fp8((long long)A7,          \
          (long long)bfr[(G)*8+7], ACC, 0, 0, 0)

#define ROWUP(J, PI, PF, PG, PO, CREG, HL) {                                 \
    float xi = __builtin_fmaf(ac0[J], INV64, PI);                            \
    float xf = __builtin_fmaf(ac1[J], INV64, PF);                            \
    float xg = __builtin_fmaf(ac2[J], INV64, PG);                            \
    float xo = __builtin_fmaf(ac3[J], INV64, PO);                            \
    CREG = __builtin_fmaf(sigmf_(xf), CREG, sigmf_(xi) * tanhf_(xg));        \
    HL = sigmf_(xo) * tanhf_(CREG);                                         \
  }

#define STEP(RB, WB) {                                                       \
    u64 A0 = *(const u64*)(hbuf + (RB) + base_a + 0);                        \
    u64 A1 = *(const u64*)(hbuf + (RB) + base_a + 32);                       \
    u64 A2 = *(const u64*)(hbuf + (RB) + base_a + 64);                       \
    u64 A3 = *(const u64*)(hbuf + (RB) + base_a + 96);                       \
    u64 A4 = *(const u64*)(hbuf + (RB) + base_a + 128);                      \
    u64 A5 = *(const u64*)(hbuf + (RB) + base_a + 160);                      \
    u64 A6 = *(const u64*)(hbuf + (RB) + base_a + 192);                      \
    u64 A7 = *(const u64*)(hbuf + (RB) + base_a + 224);                      \
    uint2 p0 = *(const uint2*)(pp + 0);                                      \
    uint2 p1 = *(const uint2*)(pp + 512);                                    \
    uint2 p2 = *(const uint2*)(pp + 1024);                                   \
    uint2 p3 = *(const uint2*)(pp + 1536);                                   \
    pp += PSTRIDE;                                                           \
    f32x4 ac0 = {0.f, 0.f, 0.f, 0.f};                                        \
    f32x4 ac1 = ac0, ac2 = ac0, ac3 = ac0;                                   \
    MFMA8(ac0, 0, A0,A1,A2,A3,A4,A5,A6,A7);                                  \
    MFMA8(ac1, 1, A0,A1,A2,A3,A4,A5,A6,A7);                                  \
    MFMA8(ac2, 2, A0,A1,A2,A3,A4,A5,A6,A7);                                  \
    MFMA8(ac3, 3, A0,A1,A2,A3,A4,A5,A6,A7);                                  \
    h2t p0a = bc2(p0.x), p0b = bc2(p0.y);                                    \
    h2t p1a = bc2(p1.x), p1b = bc2(p1.y);                                    \
    h2t p2a = bc2(p2.x), p2b = bc2(p2.y);                                    \
    h2t p3a = bc2(p3.x), p3b = bc2(p3.y);                                    \
    ROWUP(0, (float)p0a[0], (float)p1a[0], (float)p2a[0], (float)p3a[0],     \
          c0, hl0);                                                          \
    ROWUP(1, (float)p0a[1], (float)p1a[1], (float)p2a[1], (float)p3a[1],     \
          c1, hl1);                                                          \
    ROWUP(2, (float)p0b[0], (float)p1b[0], (float)p2b[0], (float)p3b[0],     \
          c2, hl2);                                                          \
    ROWUP(3, (float)p0b[1], (float)p1b[1], (float)p2b[1], (float)p3b[1],     \
          c3, hl3);                                                          \
    unsigned int uq = pk_fp8x2<false>(8.f * hl0, 8.f * hl1, 0u);             \
    uq = pk_fp8x2<true>(8.f * hl2, 8.f * hl3, uq);                           \
    hbuf[(WB) + base_w + 0]   = (unsigned char)(uq);                         \
    hbuf[(WB) + base_w + 272] = (unsigned char)(uq >> 8);                    \
    hbuf[(WB) + base_w + 544] = (unsigned char)(uq >> 16);                   \
    hbuf[(WB) + base_w + 816] = (unsigned char)(uq >> 24);                   \
    __syncthreads();                                                         \
  }

#pragma unroll 1
  for (int it = 0; it < 256; ++it) {
    STEP(0, 4352)                // even t: read buf0, write buf1
    STEP(4352, 0)                // odd t : read buf1, write buf0
  }
#undef STEP
#undef ROWUP
#undef MFMA8

  // --- classifier head on final h (f32 from last step) ---
  sHF[hi * 4 + 0][q] = hl0;
  sHF[hi * 4 + 1][q] = hl1;
  sHF[hi * 4 + 2][q] = hl2;
  sHF[hi * 4 + 3][q] = hl3;
  __syncthreads();
  {
    const int o = v & 127;
    const int rr = v >> 7;                     // 0..7 -> rows rr, rr+8
    float acc0 = b_fc[o], acc1 = acc0;
    const f32x4* wp = (const f32x4*)(W_fc + (size_t)o * 256);
    const f32x4* hA = (const f32x4*)(&sHF[rr][0]);
    const f32x4* hB = (const f32x4*)(&sHF[rr + 8][0]);
#pragma unroll 8
    for (int s = 0; s < 64; ++s) {
      f32x4 wq = wp[s];
      f32x4 ha = hA[s];
      f32x4 hb = hB[s];
      acc0 += wq[0]*ha[0] + wq[1]*ha[1] + wq[2]*ha[2] + wq[3]*ha[3];
      acc1 += wq[0]*hb[0] + wq[1]*hb[1] + wq[2]*hb[2] + wq[3]*hb[3];
    }
    out[((size_t)b * 16 + rr) * 128 + o] = acc0;
    out[((size_t)b * 16 + rr + 8) * 128 + o] = acc1;
  }
}

extern "C" void kernel_launch(void* const* d_in, const int* in_sizes, int n_in,
                              void* d_out, int out_size, void* d_ws,
                              size_t ws_size, hipStream_t stream) {
  const float* x    = (const float*)d_in[0];
  // d_in[1] = input_lengths: unused by the reference
  const float* W_ih = (const float*)d_in[2];
  const float* W_hh = (const float*)d_in[3];
  const float* b_ih = (const float*)d_in[4];
  const float* b_hh = (const float*)d_in[5];
  // d_in[6] = W_xi, d_in[7] = b_xi: dead code in the reference
  const float* W_fc = (const float*)d_in[8];
  const float* b_fc = (const float*)d_in[9];
  unsigned char* ws = (unsigned char*)d_ws;

  if (ws_size < WS_NEED) return;  // signature: output stays poisoned

  prep_w<<<128, 256, 0, stream>>>(W_hh, ws);
  prep_p<<<512, 1024, 0, stream>>>(x, W_ih, b_ih, b_hh, ws);
  scan_k<<<8, 1024, 0, stream>>>(ws, W_fc, b_fc, (float*)d_out);
}